// Round 13
// baseline (768.927 us; speedup 1.0000x reference)
//
#include <hip/hip_runtime.h>

#define NEG_SLOPE 0.2f

template <int CTRL>
__device__ __forceinline__ float dppadd(float x) {
    int y = __builtin_amdgcn_update_dpp(0, __float_as_int(x), CTRL, 0xf, 0xf, true);
    return x + __int_as_float(y);
}

__device__ __forceinline__ unsigned short f2bf(float f) {
    unsigned u = __float_as_uint(f);
    u = (u + 0x7FFFu + ((u >> 16) & 1u)) >> 16;   // round-to-nearest-even
    return (unsigned short)u;
}
__device__ __forceinline__ float bf2f(unsigned short h) {
    return __uint_as_float(((unsigned)h) << 16);
}

// ---------------- K1: fused node encoder + xl(bf16)/xr(f32) + degree histogram ----------------
// blocks [0, encB) do the encoder; blocks [encB, encB+degB) do the degree histogram.
__global__ void __launch_bounds__(256) k_enc_deg(
    const float* __restrict__ x, const int* __restrict__ node_type,
    const float* __restrict__ type_emb,
    const float* __restrict__ enc_W, const float* __restrict__ enc_b,
    const float* __restrict__ Wl, const float* __restrict__ bl,
    const float* __restrict__ Wr, const float* __restrict__ br,
    unsigned short* __restrict__ xl, float* __restrict__ xr, int N,
    const int* __restrict__ dst, int* __restrict__ degi, int E, int encB) {
    if (blockIdx.x >= (unsigned)encB) {
        int e = (blockIdx.x - encB) * 256 + threadIdx.x;
        if (e < E) atomicAdd(&degi[dst[e]], 1);
        return;
    }
    const int NPB = 16;
    __shared__ float sIn[NPB][10];
    __shared__ float sH[NPB][64];
    int tid = threadIdx.x;
    int v0 = blockIdx.x * NPB;
    for (int i = tid; i < NPB * 10; i += 256) {
        int v = i / 10, k = i % 10;
        int vg = v0 + v;
        float val = 0.f;
        if (vg < N) {
            if (k < 6) val = x[(size_t)vg * 6 + k];
            else       val = type_emb[node_type[vg] * 4 + (k - 6)];
        }
        sIn[v][k] = val;
    }
    __syncthreads();
    for (int i = tid; i < NPB * 64; i += 256) {
        int v = i >> 6, j = i & 63;
        float acc = enc_b[j];
#pragma unroll
        for (int k = 0; k < 10; ++k) acc += sIn[v][k] * enc_W[k * 64 + j];
        sH[v][j] = fmaxf(acc, 0.f);
    }
    __syncthreads();
    int j = tid;
    float accL[NPB], accR[NPB];
    float blj = bl[j], brj = br[j];
#pragma unroll
    for (int v = 0; v < NPB; ++v) { accL[v] = blj; accR[v] = brj; }
    for (int k = 0; k < 64; ++k) {
        float wl = Wl[k * 256 + j], wr = Wr[k * 256 + j];
#pragma unroll
        for (int v = 0; v < NPB; ++v) {
            float hv = sH[v][k];
            accL[v] += hv * wl;
            accR[v] += hv * wr;
        }
    }
#pragma unroll
    for (int v = 0; v < NPB; ++v) {
        int vg = v0 + v;
        if (vg < N) {
            xl[(size_t)vg * 256 + j] = f2bf(accL[v]);
            xr[(size_t)vg * 256 + j] = accR[v];
        }
    }
}

// ---------------- K2a: per-block scan (1024 elems/block) ----------------
__global__ void __launch_bounds__(1024) k_scan1(const int* __restrict__ degi,
                                                int* __restrict__ row_ptr,
                                                int* __restrict__ bsum, int N) {
    __shared__ int wsum[16];
    int tid = threadIdx.x, lane = tid & 63, wid = tid >> 6;
    int i = blockIdx.x * 1024 + tid;
    int v = (i < N) ? degi[i] : 0;
    int x = v;
#pragma unroll
    for (int off = 1; off < 64; off <<= 1) {
        int y = __shfl_up(x, off, 64);
        if (lane >= off) x += y;
    }
    if (lane == 63) wsum[wid] = x;
    __syncthreads();
    if (wid == 0) {
        int w = (lane < 16) ? wsum[lane] : 0;
#pragma unroll
        for (int off = 1; off < 16; off <<= 1) {
            int y = __shfl_up(w, off, 64);
            if (lane >= off) w += y;
        }
        if (lane < 16) wsum[lane] = w;
    }
    __syncthreads();
    int wofs = (wid > 0) ? wsum[wid - 1] : 0;
    if (i < N) row_ptr[i] = wofs + x - v;  // block-local exclusive
    if (tid == 0) bsum[blockIdx.x] = wsum[15];
}

// ---------------- K2b: scan of block sums (<=64 blocks) ----------------
__global__ void k_scan2(int* __restrict__ bsum, int* __restrict__ row_ptr, int nb, int N) {
    int lane = threadIdx.x & 63;
    int v = (lane < nb) ? bsum[lane] : 0;
    int x = v;
#pragma unroll
    for (int off = 1; off < 64; off <<= 1) {
        int y = __shfl_up(x, off, 64);
        if (lane >= off) x += y;
    }
    if (lane < nb) bsum[lane] = x - v;  // exclusive
    if (lane == 63) row_ptr[N] = x;     // grand total
}

// ---------------- K2c: apply block offsets ----------------
__global__ void __launch_bounds__(1024) k_scan3(int* __restrict__ row_ptr,
                                                int* __restrict__ cursor,
                                                const int* __restrict__ bsum, int N) {
    int i = blockIdx.x * 1024 + threadIdx.x;
    if (i < N) {
        int r = row_ptr[i] + bsum[blockIdx.x];
        row_ptr[i] = r;
        cursor[i] = r;
    }
}

// ---------------- K3: CSR fill with (src, edge_id) pairs ----------------
__global__ void k_fill(const int* __restrict__ src, const int* __restrict__ dst,
                       int* __restrict__ cursor, int2* __restrict__ csr, int E) {
    int e = blockIdx.x * blockDim.x + threadIdx.x;
    if (e >= E) return;
    int d = dst[e];
    int pos = atomicAdd(&cursor[d], 1);
    csr[pos] = make_int2(src[e], e);
}

// ---------------- K5: fused per-(node,head) GATv2; batch-4 SoA edges; bf16 xl ----------------
// block = one node; wave w = head w; lane = col within head. 32-bit addressing.
__global__ void __launch_bounds__(256, 8) k_gather(
    const int2* __restrict__ csr, const float* __restrict__ edge_attr,
    const int* __restrict__ row_ptr, const float* __restrict__ We,
    const float* __restrict__ att, const unsigned short* __restrict__ xl,
    const float* __restrict__ xr, const float* __restrict__ conv_bias,
    const int* __restrict__ batch, float* __restrict__ pooled,
    float* __restrict__ gcnt, int N) {
    __shared__ float sO[4][64];
    int tid = threadIdx.x;
    int lane = tid & 63;
    int h = tid >> 6;
    int v = blockIdx.x;
    unsigned col = (unsigned)(h * 64 + lane);

    float rWe[11];
#pragma unroll
    for (int k = 0; k < 11; ++k) rWe[k] = We[k * 256 + col];
    float attC = att[col];
    float xrC = xr[(unsigned)v * 256u + col];

    float acc = 0.f, den = 0.f, eaC = 0.f;

    int rs = row_ptr[v], re = row_ptr[v + 1];
    int deg = re - rs;

    for (int base = rs; base < re; base += 64) {
        int cnt = re - base; if (cnt > 64) cnt = 64;
        int cm1 = cnt - 1;
        int2 se = csr[base + ((lane < cnt) ? lane : cm1)];
        int myS = se.x, myE = se.y;

        for (int t0 = 0; t0 < cnt; t0 += 4) {
            int i1 = t0 + 1; if (i1 > cm1) i1 = cm1;
            int i2 = t0 + 2; if (i2 > cm1) i2 = cm1;
            int i3 = t0 + 3; if (i3 > cm1) i3 = cm1;
            unsigned s0 = (unsigned)__builtin_amdgcn_readlane(myS, t0);
            unsigned s1 = (unsigned)__builtin_amdgcn_readlane(myS, i1);
            unsigned s2 = (unsigned)__builtin_amdgcn_readlane(myS, i2);
            unsigned s3 = (unsigned)__builtin_amdgcn_readlane(myS, i3);
            unsigned e0 = (unsigned)__builtin_amdgcn_readlane(myE, t0);
            unsigned e1 = (unsigned)__builtin_amdgcn_readlane(myE, i1);
            unsigned e2 = (unsigned)__builtin_amdgcn_readlane(myE, i2);
            unsigned e3 = (unsigned)__builtin_amdgcn_readlane(myE, i3);

            float x0 = bf2f(xl[s0 * 256u + col]);
            float x1 = bf2f(xl[s1 * 256u + col]);
            float x2 = bf2f(xl[s2 * 256u + col]);
            float x3 = bf2f(xl[s3 * 256u + col]);

            const float* a0p = edge_attr + e0 * 11u;
            const float* a1p = edge_attr + e1 * 11u;
            const float* a2p = edge_attr + e2 * 11u;
            const float* a3p = edge_attr + e3 * 11u;

            float ee0 = xrC, ee1 = xrC, ee2 = xrC, ee3 = xrC;
#pragma unroll
            for (int k = 0; k < 11; ++k) {
                float w = rWe[k];
                ee0 += a0p[k] * w;
                ee1 += a1p[k] * w;
                ee2 += a2p[k] * w;
                ee3 += a3p[k] * w;
            }
            bool v1 = (t0 + 1 < cnt), v2 = (t0 + 2 < cnt), v3 = (t0 + 3 < cnt);
            eaC += ee0 + (v1 ? ee1 : 0.f) + (v2 ? ee2 : 0.f) + (v3 ? ee3 : 0.f);

            float m0 = x0 + ee0; m0 = fmaxf(m0, NEG_SLOPE * m0);
            float m1 = x1 + ee1; m1 = fmaxf(m1, NEG_SLOPE * m1);
            float m2 = x2 + ee2; m2 = fmaxf(m2, NEG_SLOPE * m2);
            float m3 = x3 + ee3; m3 = fmaxf(m3, NEG_SLOPE * m3);
            float t20 = m0 * attC, t21 = m1 * attC, t22 = m2 * attC, t23 = m3 * attC;

            t20 = dppadd<0xB1>(t20);  t21 = dppadd<0xB1>(t21);
            t22 = dppadd<0xB1>(t22);  t23 = dppadd<0xB1>(t23);
            t20 = dppadd<0x4E>(t20);  t21 = dppadd<0x4E>(t21);
            t22 = dppadd<0x4E>(t22);  t23 = dppadd<0x4E>(t23);
            t20 = dppadd<0x141>(t20); t21 = dppadd<0x141>(t21);
            t22 = dppadd<0x141>(t22); t23 = dppadd<0x141>(t23);
            t20 = dppadd<0x140>(t20); t21 = dppadd<0x140>(t21);
            t22 = dppadd<0x140>(t22); t23 = dppadd<0x140>(t23);
            t20 += __shfl_xor(t20, 16, 64); t21 += __shfl_xor(t21, 16, 64);
            t22 += __shfl_xor(t22, 16, 64); t23 += __shfl_xor(t23, 16, 64);
            t20 += __shfl_xor(t20, 32, 64); t21 += __shfl_xor(t21, 32, 64);
            t22 += __shfl_xor(t22, 32, 64); t23 += __shfl_xor(t23, 32, 64);

            float p0 = __expf(t20);
            float p1 = v1 ? __expf(t21) : 0.f;
            float p2 = v2 ? __expf(t22) : 0.f;
            float p3 = v3 ? __expf(t23) : 0.f;
            acc += p0 * x0; den += p0;
            acc += p1 * x1; den += p1;
            acc += p2 * x2; den += p2;
            acc += p3 * x3; den += p3;
        }
    }

    // self-loop: ee_self = xrC + mean(We.a) = eaC/deg (seeded chain); deg=0 -> xrC
    {
        float xs = bf2f(xl[(unsigned)v * 256u + col]);
        float eeS = (deg > 0) ? (eaC * (1.0f / (float)deg)) : xrC;
        float m = xs + eeS;
        m = fmaxf(m, NEG_SLOPE * m);
        float t2 = m * attC;
        t2 = dppadd<0xB1>(t2);
        t2 = dppadd<0x4E>(t2);
        t2 = dppadd<0x141>(t2);
        t2 = dppadd<0x140>(t2);
        t2 += __shfl_xor(t2, 16, 64);
        t2 += __shfl_xor(t2, 32, 64);
        float p = __expf(t2);
        acc += p * xs;
        den += p;
    }

    sO[h][lane] = acc / (den + 1e-16f);
    __syncthreads();
    if (tid < 64) {
        float s4 = sO[0][lane] + sO[1][lane] + sO[2][lane] + sO[3][lane];
        float hc = fmaxf(0.25f * s4 + conv_bias[lane], 0.f);
        int g = batch[v];
        atomicAdd(&pooled[g * 64 + lane], hc);
        if (lane == 0) atomicAdd(&gcnt[g], 1.0f);
    }
}

// ---------------- K6: per-graph MLP head ----------------
__global__ void k_final(const float* __restrict__ pooled, const float* __restrict__ gcnt,
                        const float* __restrict__ gf, const float* __restrict__ gW,
                        const float* __restrict__ gb, const float* __restrict__ h1W,
                        const float* __restrict__ h1b, const float* __restrict__ h2W,
                        const float* __restrict__ h2b, float* __restrict__ out, int G) {
    __shared__ float sComb[128];
    __shared__ float sHid[64];
    int g = blockIdx.x;
    int t = threadIdx.x;
    if (t < 64) {
        sComb[t] = pooled[(size_t)g * 64 + t] / fmaxf(gcnt[g], 1.0f);
    } else {
        int j = t - 64;
        float acc = gb[j];
#pragma unroll
        for (int k = 0; k < 6; ++k) acc += gf[(size_t)g * 6 + k] * gW[k * 64 + j];
        sComb[64 + j] = fmaxf(acc, 0.f);
    }
    __syncthreads();
    if (t < 64) {
        float acc = h1b[t];
#pragma unroll
        for (int k = 0; k < 128; ++k) acc += sComb[k] * h1W[k * 64 + t];
        sHid[t] = fmaxf(acc, 0.f);
    }
    __syncthreads();
    if (t < 64) {
        float p = sHid[t] * h2W[t];
#pragma unroll
        for (int off = 32; off > 0; off >>= 1) p += __shfl_xor(p, off, 64);
        if (t == 0) out[g] = p + h2b[0];
    }
}

extern "C" void kernel_launch(void* const* d_in, const int* in_sizes, int n_in,
                              void* d_out, int out_size, void* d_ws, size_t ws_size,
                              hipStream_t stream) {
    const float* x         = (const float*)d_in[0];
    const int*   node_type = (const int*)d_in[1];
    const int*   edge_index= (const int*)d_in[2];
    const float* edge_attr = (const float*)d_in[3];
    const int*   batch     = (const int*)d_in[4];
    const float* gf        = (const float*)d_in[5];
    const float* type_emb  = (const float*)d_in[6];
    const float* enc_W     = (const float*)d_in[7];
    const float* enc_b     = (const float*)d_in[8];
    const float* Wl        = (const float*)d_in[9];
    const float* bl        = (const float*)d_in[10];
    const float* Wr        = (const float*)d_in[11];
    const float* br        = (const float*)d_in[12];
    const float* We        = (const float*)d_in[13];
    const float* att       = (const float*)d_in[14];
    const float* conv_bias = (const float*)d_in[15];
    const float* gW        = (const float*)d_in[16];
    const float* gb        = (const float*)d_in[17];
    const float* h1W       = (const float*)d_in[18];
    const float* h1b       = (const float*)d_in[19];
    const float* h2W       = (const float*)d_in[20];
    const float* h2b       = (const float*)d_in[21];
    float* out = (float*)d_out;

    const int N = in_sizes[0] / 6;
    const int E = in_sizes[2] / 2;
    const int G = in_sizes[5] / 6;

    const int* srcArr = edge_index;
    const int* dstArr = edge_index + E;

    // workspace layout
    char* wsb = (char*)d_ws;
    size_t off = 0;
    float* xr      = (float*)(wsb + off); off += (size_t)N * 256 * 4;
    unsigned short* xlb = (unsigned short*)(wsb + off); off += (size_t)N * 256 * 2;
    int2*  csr     = (int2*) (wsb + off); off += (size_t)E * 8;
    int*   row_ptr = (int*)  (wsb + off); off += (size_t)(N + 1) * 4;
    int*   cursor  = (int*)  (wsb + off); off += (size_t)N * 4;
    int*   bsum    = (int*)  (wsb + off); off += 64 * 4;
    size_t zs = off;  // ---- zeroed region ----
    int*   degi    = (int*)  (wsb + off); off += (size_t)N * 4;
    float* pooled  = (float*)(wsb + off); off += (size_t)G * 64 * 4;
    float* gcnt    = (float*)(wsb + off); off += (size_t)G * 4;
    size_t ze = off;
    (void)ws_size; (void)n_in; (void)out_size;

    (void)hipMemsetAsync(wsb + zs, 0, ze - zs, stream);

    const int nb1 = (N + 1023) / 1024;  // <= 64 for N <= 65536
    const int encB = (N + 15) / 16;
    const int degB = (E + 255) / 256;
    k_enc_deg<<<encB + degB, 256, 0, stream>>>(x, node_type, type_emb, enc_W, enc_b,
                                               Wl, bl, Wr, br, xlb, xr, N,
                                               dstArr, degi, E, encB);
    k_scan1<<<nb1, 1024, 0, stream>>>(degi, row_ptr, bsum, N);
    k_scan2<<<1, 64, 0, stream>>>(bsum, row_ptr, nb1, N);
    k_scan3<<<nb1, 1024, 0, stream>>>(row_ptr, cursor, bsum, N);
    k_fill<<<(E + 255) / 256, 256, 0, stream>>>(srcArr, dstArr, cursor, csr, E);
    k_gather<<<N, 256, 0, stream>>>(csr, edge_attr, row_ptr, We, att, xlb, xr,
                                    conv_bias, batch, pooled, gcnt, N);
    k_final<<<G, 128, 0, stream>>>(pooled, gcnt, gf, gW, gb, h1W, h1b, h2W, h2b, out, G);
}

// Round 14
// 715.517 us; speedup vs baseline: 1.0746x; 1.0746x over previous
//
#include <hip/hip_runtime.h>

#define NEG_SLOPE 0.2f

template <int CTRL>
__device__ __forceinline__ float dppadd(float x) {
    int y = __builtin_amdgcn_update_dpp(0, __float_as_int(x), CTRL, 0xf, 0xf, true);
    return x + __int_as_float(y);
}

__device__ __forceinline__ unsigned short f2bf(float f) {
    unsigned u = __float_as_uint(f);
    u = (u + 0x7FFFu + ((u >> 16) & 1u)) >> 16;   // round-to-nearest-even
    return (unsigned short)u;
}
__device__ __forceinline__ float bf2f(unsigned short h) {
    return __uint_as_float(((unsigned)h) << 16);
}

// ---------------- K1: fused node encoder + xl(bf16)/xr(f32) + degree histogram ----------------
// blocks [0, encB) do the encoder; blocks [encB, encB+degB) do the degree histogram.
__global__ void __launch_bounds__(256) k_enc_deg(
    const float* __restrict__ x, const int* __restrict__ node_type,
    const float* __restrict__ type_emb,
    const float* __restrict__ enc_W, const float* __restrict__ enc_b,
    const float* __restrict__ Wl, const float* __restrict__ bl,
    const float* __restrict__ Wr, const float* __restrict__ br,
    unsigned short* __restrict__ xl, float* __restrict__ xr, int N,
    const int* __restrict__ dst, int* __restrict__ degi, int E, int encB) {
    if (blockIdx.x >= (unsigned)encB) {
        int e = (blockIdx.x - encB) * 256 + threadIdx.x;
        if (e < E) atomicAdd(&degi[dst[e]], 1);
        return;
    }
    const int NPB = 16;
    __shared__ float sIn[NPB][10];
    __shared__ float sH[NPB][64];
    int tid = threadIdx.x;
    int v0 = blockIdx.x * NPB;
    for (int i = tid; i < NPB * 10; i += 256) {
        int v = i / 10, k = i % 10;
        int vg = v0 + v;
        float val = 0.f;
        if (vg < N) {
            if (k < 6) val = x[(size_t)vg * 6 + k];
            else       val = type_emb[node_type[vg] * 4 + (k - 6)];
        }
        sIn[v][k] = val;
    }
    __syncthreads();
    for (int i = tid; i < NPB * 64; i += 256) {
        int v = i >> 6, j = i & 63;
        float acc = enc_b[j];
#pragma unroll
        for (int k = 0; k < 10; ++k) acc += sIn[v][k] * enc_W[k * 64 + j];
        sH[v][j] = fmaxf(acc, 0.f);
    }
    __syncthreads();
    int j = tid;
    float accL[NPB], accR[NPB];
    float blj = bl[j], brj = br[j];
#pragma unroll
    for (int v = 0; v < NPB; ++v) { accL[v] = blj; accR[v] = brj; }
    for (int k = 0; k < 64; ++k) {
        float wl = Wl[k * 256 + j], wr = Wr[k * 256 + j];
#pragma unroll
        for (int v = 0; v < NPB; ++v) {
            float hv = sH[v][k];
            accL[v] += hv * wl;
            accR[v] += hv * wr;
        }
    }
#pragma unroll
    for (int v = 0; v < NPB; ++v) {
        int vg = v0 + v;
        if (vg < N) {
            xl[(size_t)vg * 256 + j] = f2bf(accL[v]);
            xr[(size_t)vg * 256 + j] = accR[v];
        }
    }
}

// ---------------- K2a: per-block scan (1024 elems/block) ----------------
__global__ void __launch_bounds__(1024) k_scan1(const int* __restrict__ degi,
                                                int* __restrict__ row_ptr,
                                                int* __restrict__ bsum, int N) {
    __shared__ int wsum[16];
    int tid = threadIdx.x, lane = tid & 63, wid = tid >> 6;
    int i = blockIdx.x * 1024 + tid;
    int v = (i < N) ? degi[i] : 0;
    int x = v;
#pragma unroll
    for (int off = 1; off < 64; off <<= 1) {
        int y = __shfl_up(x, off, 64);
        if (lane >= off) x += y;
    }
    if (lane == 63) wsum[wid] = x;
    __syncthreads();
    if (wid == 0) {
        int w = (lane < 16) ? wsum[lane] : 0;
#pragma unroll
        for (int off = 1; off < 16; off <<= 1) {
            int y = __shfl_up(w, off, 64);
            if (lane >= off) w += y;
        }
        if (lane < 16) wsum[lane] = w;
    }
    __syncthreads();
    int wofs = (wid > 0) ? wsum[wid - 1] : 0;
    if (i < N) row_ptr[i] = wofs + x - v;  // block-local exclusive
    if (tid == 0) bsum[blockIdx.x] = wsum[15];
}

// ---------------- K2b: scan of block sums (<=64 blocks) ----------------
__global__ void k_scan2(int* __restrict__ bsum, int* __restrict__ row_ptr, int nb, int N) {
    int lane = threadIdx.x & 63;
    int v = (lane < nb) ? bsum[lane] : 0;
    int x = v;
#pragma unroll
    for (int off = 1; off < 64; off <<= 1) {
        int y = __shfl_up(x, off, 64);
        if (lane >= off) x += y;
    }
    if (lane < nb) bsum[lane] = x - v;  // exclusive
    if (lane == 63) row_ptr[N] = x;     // grand total
}

// ---------------- K2c: apply block offsets ----------------
__global__ void __launch_bounds__(1024) k_scan3(int* __restrict__ row_ptr,
                                                int* __restrict__ cursor,
                                                const int* __restrict__ bsum, int N) {
    int i = blockIdx.x * 1024 + threadIdx.x;
    if (i < N) {
        int r = row_ptr[i] + bsum[blockIdx.x];
        row_ptr[i] = r;
        cursor[i] = r;
    }
}

// ---------------- K3: CSR fill with (src, edge_id) pairs ----------------
__global__ void k_fill(const int* __restrict__ src, const int* __restrict__ dst,
                       int* __restrict__ cursor, int2* __restrict__ csr, int E) {
    int e = blockIdx.x * blockDim.x + threadIdx.x;
    if (e >= E) return;
    int d = dst[e];
    int pos = atomicAdd(&cursor[d], 1);
    csr[pos] = make_int2(src[e], e);
}

// ---------------- K5: fused per-(node,head) GATv2; batch-4 SoA edges; bf16 xl ----------------
// block = one node; wave w = head w; lane = col within head. 32-bit addressing.
__global__ void __launch_bounds__(256, 6) k_gather(
    const int2* __restrict__ csr, const float* __restrict__ edge_attr,
    const int* __restrict__ row_ptr, const float* __restrict__ We,
    const float* __restrict__ att, const unsigned short* __restrict__ xl,
    const float* __restrict__ xr, const float* __restrict__ conv_bias,
    const int* __restrict__ batch, float* __restrict__ pooled,
    float* __restrict__ gcnt, int N) {
    __shared__ float sO[4][64];
    int tid = threadIdx.x;
    int lane = tid & 63;
    int h = tid >> 6;
    int v = blockIdx.x;
    unsigned col = (unsigned)(h * 64 + lane);

    float rWe[11];
#pragma unroll
    for (int k = 0; k < 11; ++k) rWe[k] = We[k * 256 + col];
    float attC = att[col];
    float xrC = xr[(unsigned)v * 256u + col];

    float acc = 0.f, den = 0.f, eaC = 0.f;

    int rs = row_ptr[v], re = row_ptr[v + 1];
    int deg = re - rs;

    for (int base = rs; base < re; base += 64) {
        int cnt = re - base; if (cnt > 64) cnt = 64;
        int cm1 = cnt - 1;
        int2 se = csr[base + ((lane < cnt) ? lane : cm1)];
        int myS = se.x, myE = se.y;

        for (int t0 = 0; t0 < cnt; t0 += 4) {
            int i1 = t0 + 1; if (i1 > cm1) i1 = cm1;
            int i2 = t0 + 2; if (i2 > cm1) i2 = cm1;
            int i3 = t0 + 3; if (i3 > cm1) i3 = cm1;
            unsigned s0 = (unsigned)__builtin_amdgcn_readlane(myS, t0);
            unsigned s1 = (unsigned)__builtin_amdgcn_readlane(myS, i1);
            unsigned s2 = (unsigned)__builtin_amdgcn_readlane(myS, i2);
            unsigned s3 = (unsigned)__builtin_amdgcn_readlane(myS, i3);
            unsigned e0 = (unsigned)__builtin_amdgcn_readlane(myE, t0);
            unsigned e1 = (unsigned)__builtin_amdgcn_readlane(myE, i1);
            unsigned e2 = (unsigned)__builtin_amdgcn_readlane(myE, i2);
            unsigned e3 = (unsigned)__builtin_amdgcn_readlane(myE, i3);

            float x0 = bf2f(xl[s0 * 256u + col]);
            float x1 = bf2f(xl[s1 * 256u + col]);
            float x2 = bf2f(xl[s2 * 256u + col]);
            float x3 = bf2f(xl[s3 * 256u + col]);

            const float* a0p = edge_attr + e0 * 11u;
            const float* a1p = edge_attr + e1 * 11u;
            const float* a2p = edge_attr + e2 * 11u;
            const float* a3p = edge_attr + e3 * 11u;

            float ee0 = xrC, ee1 = xrC, ee2 = xrC, ee3 = xrC;
#pragma unroll
            for (int k = 0; k < 11; ++k) {
                float w = rWe[k];
                ee0 += a0p[k] * w;
                ee1 += a1p[k] * w;
                ee2 += a2p[k] * w;
                ee3 += a3p[k] * w;
            }
            bool v1 = (t0 + 1 < cnt), v2 = (t0 + 2 < cnt), v3 = (t0 + 3 < cnt);
            eaC += ee0 + (v1 ? ee1 : 0.f) + (v2 ? ee2 : 0.f) + (v3 ? ee3 : 0.f);

            float m0 = x0 + ee0; m0 = fmaxf(m0, NEG_SLOPE * m0);
            float m1 = x1 + ee1; m1 = fmaxf(m1, NEG_SLOPE * m1);
            float m2 = x2 + ee2; m2 = fmaxf(m2, NEG_SLOPE * m2);
            float m3 = x3 + ee3; m3 = fmaxf(m3, NEG_SLOPE * m3);
            float t20 = m0 * attC, t21 = m1 * attC, t22 = m2 * attC, t23 = m3 * attC;

            t20 = dppadd<0xB1>(t20);  t21 = dppadd<0xB1>(t21);
            t22 = dppadd<0xB1>(t22);  t23 = dppadd<0xB1>(t23);
            t20 = dppadd<0x4E>(t20);  t21 = dppadd<0x4E>(t21);
            t22 = dppadd<0x4E>(t22);  t23 = dppadd<0x4E>(t23);
            t20 = dppadd<0x141>(t20); t21 = dppadd<0x141>(t21);
            t22 = dppadd<0x141>(t22); t23 = dppadd<0x141>(t23);
            t20 = dppadd<0x140>(t20); t21 = dppadd<0x140>(t21);
            t22 = dppadd<0x140>(t22); t23 = dppadd<0x140>(t23);
            t20 += __shfl_xor(t20, 16, 64); t21 += __shfl_xor(t21, 16, 64);
            t22 += __shfl_xor(t22, 16, 64); t23 += __shfl_xor(t23, 16, 64);
            t20 += __shfl_xor(t20, 32, 64); t21 += __shfl_xor(t21, 32, 64);
            t22 += __shfl_xor(t22, 32, 64); t23 += __shfl_xor(t23, 32, 64);

            float p0 = __expf(t20);
            float p1 = v1 ? __expf(t21) : 0.f;
            float p2 = v2 ? __expf(t22) : 0.f;
            float p3 = v3 ? __expf(t23) : 0.f;
            acc += p0 * x0; den += p0;
            acc += p1 * x1; den += p1;
            acc += p2 * x2; den += p2;
            acc += p3 * x3; den += p3;
        }
    }

    // self-loop: ee_self = xrC + mean(We.a) = eaC/deg (seeded chain); deg=0 -> xrC
    {
        float xs = bf2f(xl[(unsigned)v * 256u + col]);
        float eeS = (deg > 0) ? (eaC * (1.0f / (float)deg)) : xrC;
        float m = xs + eeS;
        m = fmaxf(m, NEG_SLOPE * m);
        float t2 = m * attC;
        t2 = dppadd<0xB1>(t2);
        t2 = dppadd<0x4E>(t2);
        t2 = dppadd<0x141>(t2);
        t2 = dppadd<0x140>(t2);
        t2 += __shfl_xor(t2, 16, 64);
        t2 += __shfl_xor(t2, 32, 64);
        float p = __expf(t2);
        acc += p * xs;
        den += p;
    }

    sO[h][lane] = acc / (den + 1e-16f);
    __syncthreads();
    if (tid < 64) {
        float s4 = sO[0][lane] + sO[1][lane] + sO[2][lane] + sO[3][lane];
        float hc = fmaxf(0.25f * s4 + conv_bias[lane], 0.f);
        int g = batch[v];
        atomicAdd(&pooled[g * 64 + lane], hc);
        if (lane == 0) atomicAdd(&gcnt[g], 1.0f);
    }
}

// ---------------- K6: per-graph MLP head ----------------
__global__ void k_final(const float* __restrict__ pooled, const float* __restrict__ gcnt,
                        const float* __restrict__ gf, const float* __restrict__ gW,
                        const float* __restrict__ gb, const float* __restrict__ h1W,
                        const float* __restrict__ h1b, const float* __restrict__ h2W,
                        const float* __restrict__ h2b, float* __restrict__ out, int G) {
    __shared__ float sComb[128];
    __shared__ float sHid[64];
    int g = blockIdx.x;
    int t = threadIdx.x;
    if (t < 64) {
        sComb[t] = pooled[(size_t)g * 64 + t] / fmaxf(gcnt[g], 1.0f);
    } else {
        int j = t - 64;
        float acc = gb[j];
#pragma unroll
        for (int k = 0; k < 6; ++k) acc += gf[(size_t)g * 6 + k] * gW[k * 64 + j];
        sComb[64 + j] = fmaxf(acc, 0.f);
    }
    __syncthreads();
    if (t < 64) {
        float acc = h1b[t];
#pragma unroll
        for (int k = 0; k < 128; ++k) acc += sComb[k] * h1W[k * 64 + t];
        sHid[t] = fmaxf(acc, 0.f);
    }
    __syncthreads();
    if (t < 64) {
        float p = sHid[t] * h2W[t];
#pragma unroll
        for (int off = 32; off > 0; off >>= 1) p += __shfl_xor(p, off, 64);
        if (t == 0) out[g] = p + h2b[0];
    }
}

extern "C" void kernel_launch(void* const* d_in, const int* in_sizes, int n_in,
                              void* d_out, int out_size, void* d_ws, size_t ws_size,
                              hipStream_t stream) {
    const float* x         = (const float*)d_in[0];
    const int*   node_type = (const int*)d_in[1];
    const int*   edge_index= (const int*)d_in[2];
    const float* edge_attr = (const float*)d_in[3];
    const int*   batch     = (const int*)d_in[4];
    const float* gf        = (const float*)d_in[5];
    const float* type_emb  = (const float*)d_in[6];
    const float* enc_W     = (const float*)d_in[7];
    const float* enc_b     = (const float*)d_in[8];
    const float* Wl        = (const float*)d_in[9];
    const float* bl        = (const float*)d_in[10];
    const float* Wr        = (const float*)d_in[11];
    const float* br        = (const float*)d_in[12];
    const float* We        = (const float*)d_in[13];
    const float* att       = (const float*)d_in[14];
    const float* conv_bias = (const float*)d_in[15];
    const float* gW        = (const float*)d_in[16];
    const float* gb        = (const float*)d_in[17];
    const float* h1W       = (const float*)d_in[18];
    const float* h1b       = (const float*)d_in[19];
    const float* h2W       = (const float*)d_in[20];
    const float* h2b       = (const float*)d_in[21];
    float* out = (float*)d_out;

    const int N = in_sizes[0] / 6;
    const int E = in_sizes[2] / 2;
    const int G = in_sizes[5] / 6;

    const int* srcArr = edge_index;
    const int* dstArr = edge_index + E;

    // workspace layout
    char* wsb = (char*)d_ws;
    size_t off = 0;
    float* xr      = (float*)(wsb + off); off += (size_t)N * 256 * 4;
    unsigned short* xlb = (unsigned short*)(wsb + off); off += (size_t)N * 256 * 2;
    int2*  csr     = (int2*) (wsb + off); off += (size_t)E * 8;
    int*   row_ptr = (int*)  (wsb + off); off += (size_t)(N + 1) * 4;
    int*   cursor  = (int*)  (wsb + off); off += (size_t)N * 4;
    int*   bsum    = (int*)  (wsb + off); off += 64 * 4;
    size_t zs = off;  // ---- zeroed region ----
    int*   degi    = (int*)  (wsb + off); off += (size_t)N * 4;
    float* pooled  = (float*)(wsb + off); off += (size_t)G * 64 * 4;
    float* gcnt    = (float*)(wsb + off); off += (size_t)G * 4;
    size_t ze = off;
    (void)ws_size; (void)n_in; (void)out_size;

    (void)hipMemsetAsync(wsb + zs, 0, ze - zs, stream);

    const int nb1 = (N + 1023) / 1024;  // <= 64 for N <= 65536
    const int encB = (N + 15) / 16;
    const int degB = (E + 255) / 256;
    k_enc_deg<<<encB + degB, 256, 0, stream>>>(x, node_type, type_emb, enc_W, enc_b,
                                               Wl, bl, Wr, br, xlb, xr, N,
                                               dstArr, degi, E, encB);
    k_scan1<<<nb1, 1024, 0, stream>>>(degi, row_ptr, bsum, N);
    k_scan2<<<1, 64, 0, stream>>>(bsum, row_ptr, nb1, N);
    k_scan3<<<nb1, 1024, 0, stream>>>(row_ptr, cursor, bsum, N);
    k_fill<<<(E + 255) / 256, 256, 0, stream>>>(srcArr, dstArr, cursor, csr, E);
    k_gather<<<N, 256, 0, stream>>>(csr, edge_attr, row_ptr, We, att, xlb, xr,
                                    conv_bias, batch, pooled, gcnt, N);
    k_final<<<G, 128, 0, stream>>>(pooled, gcnt, gf, gW, gb, h1W, h1b, h2W, h2b, out, G);
}